// Round 4
// baseline (90.683 us; speedup 1.0000x reference)
//
#include <hip/hip_runtime.h>
#include <math.h>

#define BT    8192      // B*T = 16*512
#define IDIM  80
#define HDIM  512
#define SPAN  159       // 2*IDIM-1
#define PADX  320       // padded x buffer (zeros outside [79,158])
#define LDK   104       // LDS row stride in halfwords (bank-friendly, 16B-aligned)

typedef unsigned short ushort_t;
typedef __attribute__((ext_vector_type(8))) short short8;
typedef __attribute__((ext_vector_type(4))) float floatx4;
typedef __attribute__((ext_vector_type(4))) unsigned short ushort4v;

__device__ inline ushort_t f2bf(float f) {
    union { float f; unsigned int i; } v; v.f = f;
    unsigned int x = v.i;
    return (ushort_t)((x + 0x7fffu + ((x >> 16) & 1u)) >> 16);   // RNE
}

// ---------------- Kernel 1: sliding cosine-sim argmax + softmax ----------------
// One wave (64 lanes) per (b,t) row; 4 rows per 256-thread block.
// Window norms via exclusive prefix-scan of xp^2 (sliding-window sum),
// halving the hot-loop FMA count. Output written as bf16 (k_gemm rounds to
// bf16 anyway, so this is numerically identical end-to-end).
__global__ __launch_bounds__(256) void k_attn(const float* __restrict__ x,
                                              const float* __restrict__ y,
                                              ushort_t* __restrict__ xattn) {
    __shared__ float xp[4][PADX];    // xp[w][79+j] = x[j], zeros elsewhere
    __shared__ float ysm[4][IDIM];
    __shared__ float Pex[4][PADX];   // exclusive prefix of xp^2
    const int w    = threadIdx.x >> 6;
    const int lane = threadIdx.x & 63;
    const int row  = blockIdx.x * 4 + w;
    const float* xr = x + (size_t)row * IDIM;
    const float* yr = y + (size_t)row * IDIM;

    for (int j = lane; j < PADX; j += 64) xp[w][j] = 0.f;
    __syncthreads();
    float yy = 0.f;
    if (lane < 20) {                      // 20 float4 = 80 floats per row
        float4 xv = *(const float4*)(xr + lane * 4);
        float4 yv = *(const float4*)(yr + lane * 4);
        int b = 79 + lane * 4;
        xp[w][b + 0] = xv.x; xp[w][b + 1] = xv.y;
        xp[w][b + 2] = xv.z; xp[w][b + 3] = xv.w;
        int c = lane * 4;
        ysm[w][c + 0] = yv.x; ysm[w][c + 1] = yv.y;
        ysm[w][c + 2] = yv.z; ysm[w][c + 3] = yv.w;
        yy = yv.x * yv.x + yv.y * yv.y + yv.z * yv.z + yv.w * yv.w;
    }
    __syncthreads();
    #pragma unroll
    for (int off = 32; off; off >>= 1) yy += __shfl_xor(yy, off);

    const float* xpw = xp[w];
    const float* ysw = ysm[w];

    // exclusive prefix-scan of xp^2 over 320 elements (5 chunks of 64)
    {
        float carry = 0.f;
        #pragma unroll
        for (int k = 0; k < 5; ++k) {
            float v  = xpw[lane + 64 * k];
            float sq = v * v;
            float incl = sq;
            #pragma unroll
            for (int off = 1; off < 64; off <<= 1) {
                float t = __shfl_up(incl, off);
                if (lane >= off) incl += t;
            }
            Pex[w][64 * k + lane] = carry + incl - sq;   // exclusive prefix
            carry += __shfl(incl, 63);
        }
    }
    __syncthreads();

    // dot products: each lane handles shifts s = lane, lane+64, lane+128
    float d0 = 0.f, d1 = 0.f, d2 = 0.f;
    #pragma unroll
    for (int i = 0; i < IDIM; i += 4) {
        float4 yv = *(const float4*)&ysw[i];     // wave-broadcast b128
        d0 += yv.x * xpw[lane + i]     + yv.y * xpw[lane + i + 1]
            + yv.z * xpw[lane + i + 2] + yv.w * xpw[lane + i + 3];
        d1 += yv.x * xpw[lane + 64 + i]     + yv.y * xpw[lane + 64 + i + 1]
            + yv.z * xpw[lane + 64 + i + 2] + yv.w * xpw[lane + 64 + i + 3];
        d2 += yv.x * xpw[lane + 128 + i]     + yv.y * xpw[lane + 128 + i + 1]
            + yv.z * xpw[lane + 128 + i + 2] + yv.w * xpw[lane + 128 + i + 3];
    }
    const float* Pw = Pex[w];
    float n0 = Pw[lane + 80]  - Pw[lane];
    float n1 = Pw[lane + 144] - Pw[lane + 64];
    float n2 = Pw[lane + 208] - Pw[lane + 128];

    float s0 = (n0 > 0.f) ? d0 / sqrtf(yy * n0) : 0.f;
    float s1 = (n1 > 0.f) ? d1 / sqrtf(yy * n1) : 0.f;
    float s2 = (lane < 31) ? ((n2 > 0.f) ? d2 / sqrtf(yy * n2) : 0.f) : -INFINITY;

    // argmax, smallest index on ties (np.argmax semantics)
    float bv = s0; int bi = lane;
    if (s1 > bv) { bv = s1; bi = lane + 64; }
    if (s2 > bv) { bv = s2; bi = lane + 128; }
    #pragma unroll
    for (int off = 32; off; off >>= 1) {
        float ov = __shfl_xor(bv, off);
        int   oi = __shfl_xor(bi, off);
        if (ov > bv || (ov == bv && oi < bi)) { bv = ov; bi = oi; }
    }

    // x_aug, softmax(x_aug*y/10), x_attn
    float xa0 = xpw[bi + lane];
    float yv0 = ysw[lane];
    float z0  = (xa0 * yv0) / 10.0f;
    float xa1 = 0.f, z1 = -INFINITY;
    if (lane < 16) {
        xa1 = xpw[bi + lane + 64];
        float yv1 = ysw[lane + 64];
        z1 = (xa1 * yv1) / 10.0f;
    }
    float m = fmaxf(z0, z1);
    #pragma unroll
    for (int off = 32; off; off >>= 1) m = fmaxf(m, __shfl_xor(m, off));
    float e0 = expf(z0 - m);
    float e1 = (lane < 16) ? expf(z1 - m) : 0.f;
    float es = e0 + e1;
    #pragma unroll
    for (int off = 32; off; off >>= 1) es += __shfl_xor(es, off);
    float inv = 1.0f / es;

    ushort_t* orow = xattn + (size_t)row * IDIM;
    orow[lane] = f2bf(xa0 * (e0 * inv));
    if (lane < 16) orow[lane + 64] = f2bf(xa1 * (e1 * inv));
}

// ------------- Kernel 2: h = x_attn @ W^T + b  via bf16 MFMA 16x16x32 -------------
// Block = 256 thr (4 waves), tile 64 rows x 64 cols, K=80 zero-padded to 96.
// A arrives already in bf16 from k_attn.
__global__ __launch_bounds__(256) void k_gemm_mfma(const ushort_t* __restrict__ xattn,
                                                   const float* __restrict__ wmat,
                                                   const float* __restrict__ bias,
                                                   float* __restrict__ out) {
    __shared__ __align__(16) ushort_t Abf[64][LDK];
    __shared__ __align__(16) ushort_t Wbf[64][LDK];
    const int tid = threadIdx.x;
    const int rb  = blockIdx.x * 64;
    const int cb  = blockIdx.y * 64;

    // zero the K-pad region [80, 96)
    if (tid < 64) {
        ushort4v z = {0, 0, 0, 0};
        *(ushort4v*)&Abf[tid][80] = z; *(ushort4v*)&Abf[tid][84] = z;
        *(ushort4v*)&Abf[tid][88] = z; *(ushort4v*)&Abf[tid][92] = z;
        *(ushort4v*)&Wbf[tid][80] = z; *(ushort4v*)&Wbf[tid][84] = z;
        *(ushort4v*)&Wbf[tid][88] = z; *(ushort4v*)&Wbf[tid][92] = z;
    }
    // stage A tile: 64 rows x 80 bf16 = 640 uint4 (8 bf16 each), coalesced
    #pragma unroll
    for (int q = 0; q < 3; ++q) {
        int idx = q * 256 + tid;
        if (idx < 640) {
            int r  = idx / 10;           // 10 uint4 per row
            int kp = (idx % 10) * 8;
            uint4 v = *(const uint4*)(xattn + (size_t)(rb + r) * IDIM + kp);
            *(uint4*)&Abf[r][kp] = v;
        }
    }
    // stage + convert W tile: 64 cols x 80 fp32 = 1280 float4
    #pragma unroll
    for (int q = 0; q < 5; ++q) {
        int idx = q * 256 + tid;
        int r   = idx / 20;
        int kp  = (idx % 20) * 4;
        float4 wv = *(const float4*)(wmat + (size_t)(cb + r) * IDIM + kp);
        ushort4v wb = { f2bf(wv.x), f2bf(wv.y), f2bf(wv.z), f2bf(wv.w) };
        *(ushort4v*)&Wbf[r][kp] = wb;
    }
    __syncthreads();

    const int wv   = tid >> 6;        // wave 0..3 -> rows [16*wv, 16*wv+16)
    const int lane = tid & 63;
    const int m    = lane & 15;
    const int q4   = lane >> 4;       // quad

    // A fragments: 3 K-steps of 32
    short8 af[3];
    #pragma unroll
    for (int kt = 0; kt < 3; ++kt)
        af[kt] = *(const short8*)&Abf[16 * wv + m][q4 * 8 + kt * 32];

    floatx4 acc[4] = {{0.f,0.f,0.f,0.f}, {0.f,0.f,0.f,0.f},
                      {0.f,0.f,0.f,0.f}, {0.f,0.f,0.f,0.f}};
    #pragma unroll
    for (int ct = 0; ct < 4; ++ct) {
        #pragma unroll
        for (int kt = 0; kt < 3; ++kt) {
            short8 bf = *(const short8*)&Wbf[ct * 16 + m][q4 * 8 + kt * 32];
            acc[ct] = __builtin_amdgcn_mfma_f32_16x16x32_bf16(af[kt], bf, acc[ct], 0, 0, 0);
        }
    }

    // epilogue: C/D layout col=lane&15, row=quad*4+reg  (m89/m91-verified)
    #pragma unroll
    for (int ct = 0; ct < 4; ++ct) {
        int col = cb + ct * 16 + m;
        float bsv = bias[col];
        int row0 = rb + 16 * wv + q4 * 4;
        #pragma unroll
        for (int i = 0; i < 4; ++i)
            out[(size_t)(row0 + i) * HDIM + col] = acc[ct][i] + bsv;
    }
}

extern "C" void kernel_launch(void* const* d_in, const int* in_sizes, int n_in,
                              void* d_out, int out_size, void* d_ws, size_t ws_size,
                              hipStream_t stream) {
    const float* x  = (const float*)d_in[0];
    const float* y  = (const float*)d_in[1];
    const float* wm = (const float*)d_in[2];
    const float* bs = (const float*)d_in[3];
    float* out = (float*)d_out;
    ushort_t* xattn = (ushort_t*)d_ws;   // BT*IDIM*2 = 1.31 MB scratch (bf16)

    k_attn<<<dim3(BT / 4), 256, 0, stream>>>(x, y, xattn);
    k_gemm_mfma<<<dim3(BT / 64, HDIM / 64), 256, 0, stream>>>(xattn, wm, bs, out);
}

// Round 5
// 82.801 us; speedup vs baseline: 1.0952x; 1.0952x over previous
//
#include <hip/hip_runtime.h>
#include <math.h>

#define BT    8192      // B*T = 16*512
#define IDIM  80
#define HDIM  512
#define SPAN  159       // 2*IDIM-1
#define PADX  320       // padded x buffer (zeros outside [79,158])
#define LDK   104       // LDS row stride in halfwords (bank-friendly, 16B-aligned)

typedef unsigned short ushort_t;
typedef __attribute__((ext_vector_type(8))) short short8;
typedef __attribute__((ext_vector_type(4))) float floatx4;
typedef __attribute__((ext_vector_type(4))) unsigned short ushort4v;

__device__ inline ushort_t f2bf(float f) {
    union { float f; unsigned int i; } v; v.f = f;
    unsigned int x = v.i;
    return (ushort_t)((x + 0x7fffu + ((x >> 16) & 1u)) >> 16);   // RNE
}

// ---------------- Kernel 1: sliding cosine-sim argmax + softmax ----------------
// One wave (64 lanes) per (b,t) row; 4 rows per 256-thread block.
// Round-3 hot loop (fused dot+norm FMAs — independent ops, latency-tolerant);
// round-4's serial prefix-scan regressed and is reverted. Output bf16.
__global__ __launch_bounds__(256) void k_attn(const float* __restrict__ x,
                                              const float* __restrict__ y,
                                              ushort_t* __restrict__ xattn) {
    __shared__ float xp[4][PADX];    // xp[w][79+j] = x[j], zeros elsewhere
    __shared__ float ysm[4][IDIM];
    const int w    = threadIdx.x >> 6;
    const int lane = threadIdx.x & 63;
    const int row  = blockIdx.x * 4 + w;
    const float* xr = x + (size_t)row * IDIM;
    const float* yr = y + (size_t)row * IDIM;

    for (int j = lane; j < PADX; j += 64) xp[w][j] = 0.f;
    __syncthreads();
    float yy = 0.f;
    if (lane < 20) {                      // 20 float4 = 80 floats per row
        float4 xv = *(const float4*)(xr + lane * 4);
        float4 yv = *(const float4*)(yr + lane * 4);
        int b = 79 + lane * 4;
        xp[w][b + 0] = xv.x; xp[w][b + 1] = xv.y;
        xp[w][b + 2] = xv.z; xp[w][b + 3] = xv.w;
        int c = lane * 4;
        ysm[w][c + 0] = yv.x; ysm[w][c + 1] = yv.y;
        ysm[w][c + 2] = yv.z; ysm[w][c + 3] = yv.w;
        yy = yv.x * yv.x + yv.y * yv.y + yv.z * yv.z + yv.w * yv.w;
    }
    __syncthreads();
    #pragma unroll
    for (int off = 32; off; off >>= 1) yy += __shfl_xor(yy, off);

    const float* xpw = xp[w];
    const float* ysw = ysm[w];
    float d0 = 0.f, d1 = 0.f, d2 = 0.f, n0 = 0.f, n1 = 0.f, n2 = 0.f;
    #pragma unroll 4
    for (int i = 0; i < IDIM; ++i) {
        float yv = ysw[i];
        float a0 = xpw[lane + i];
        float a1 = xpw[lane + 64 + i];
        float a2 = xpw[lane + 128 + i];
        d0 += yv * a0; n0 += a0 * a0;
        d1 += yv * a1; n1 += a1 * a1;
        d2 += yv * a2; n2 += a2 * a2;
    }
    float s0 = (n0 > 0.f) ? d0 / sqrtf(yy * n0) : 0.f;
    float s1 = (n1 > 0.f) ? d1 / sqrtf(yy * n1) : 0.f;
    float s2 = (lane < 31) ? ((n2 > 0.f) ? d2 / sqrtf(yy * n2) : 0.f) : -INFINITY;

    // argmax, smallest index on ties (np.argmax semantics)
    float bv = s0; int bi = lane;
    if (s1 > bv) { bv = s1; bi = lane + 64; }
    if (s2 > bv) { bv = s2; bi = lane + 128; }
    #pragma unroll
    for (int off = 32; off; off >>= 1) {
        float ov = __shfl_xor(bv, off);
        int   oi = __shfl_xor(bi, off);
        if (ov > bv || (ov == bv && oi < bi)) { bv = ov; bi = oi; }
    }

    // x_aug, softmax(x_aug*y/10), x_attn
    float xa0 = xpw[bi + lane];
    float yv0 = ysw[lane];
    float z0  = (xa0 * yv0) / 10.0f;
    float xa1 = 0.f, z1 = -INFINITY;
    if (lane < 16) {
        xa1 = xpw[bi + lane + 64];
        float yv1 = ysw[lane + 64];
        z1 = (xa1 * yv1) / 10.0f;
    }
    float m = fmaxf(z0, z1);
    #pragma unroll
    for (int off = 32; off; off >>= 1) m = fmaxf(m, __shfl_xor(m, off));
    float e0 = expf(z0 - m);
    float e1 = (lane < 16) ? expf(z1 - m) : 0.f;
    float es = e0 + e1;
    #pragma unroll
    for (int off = 32; off; off >>= 1) es += __shfl_xor(es, off);
    float inv = 1.0f / es;

    ushort_t* orow = xattn + (size_t)row * IDIM;
    orow[lane] = f2bf(xa0 * (e0 * inv));
    if (lane < 16) orow[lane + 64] = f2bf(xa1 * (e1 * inv));
}

// ------------- Kernel 2: h = x_attn @ W^T + b  via bf16 MFMA 16x16x32 -------------
// Block = 256 thr (4 waves), tile 64 rows x 64 cols, K=80 zero-padded to 96.
// A arrives already in bf16 from k_attn.
__global__ __launch_bounds__(256) void k_gemm_mfma(const ushort_t* __restrict__ xattn,
                                                   const float* __restrict__ wmat,
                                                   const float* __restrict__ bias,
                                                   float* __restrict__ out) {
    __shared__ __align__(16) ushort_t Abf[64][LDK];
    __shared__ __align__(16) ushort_t Wbf[64][LDK];
    const int tid = threadIdx.x;
    const int rb  = blockIdx.x * 64;
    const int cb  = blockIdx.y * 64;

    // zero the K-pad region [80, 96)
    if (tid < 64) {
        ushort4v z = {0, 0, 0, 0};
        *(ushort4v*)&Abf[tid][80] = z; *(ushort4v*)&Abf[tid][84] = z;
        *(ushort4v*)&Abf[tid][88] = z; *(ushort4v*)&Abf[tid][92] = z;
        *(ushort4v*)&Wbf[tid][80] = z; *(ushort4v*)&Wbf[tid][84] = z;
        *(ushort4v*)&Wbf[tid][88] = z; *(ushort4v*)&Wbf[tid][92] = z;
    }
    // stage A tile: 64 rows x 80 bf16 = 640 uint4 (8 bf16 each), coalesced
    #pragma unroll
    for (int q = 0; q < 3; ++q) {
        int idx = q * 256 + tid;
        if (idx < 640) {
            int r  = idx / 10;           // 10 uint4 per row
            int kp = (idx % 10) * 8;
            uint4 v = *(const uint4*)(xattn + (size_t)(rb + r) * IDIM + kp);
            *(uint4*)&Abf[r][kp] = v;
        }
    }
    // stage + convert W tile: 64 cols x 80 fp32 = 1280 float4
    #pragma unroll
    for (int q = 0; q < 5; ++q) {
        int idx = q * 256 + tid;
        int r   = idx / 20;
        int kp  = (idx % 20) * 4;
        float4 wv = *(const float4*)(wmat + (size_t)(cb + r) * IDIM + kp);
        ushort4v wb = { f2bf(wv.x), f2bf(wv.y), f2bf(wv.z), f2bf(wv.w) };
        *(ushort4v*)&Wbf[r][kp] = wb;
    }
    __syncthreads();

    const int wv   = tid >> 6;        // wave 0..3 -> rows [16*wv, 16*wv+16)
    const int lane = tid & 63;
    const int m    = lane & 15;
    const int q4   = lane >> 4;       // quad

    // A fragments: 3 K-steps of 32
    short8 af[3];
    #pragma unroll
    for (int kt = 0; kt < 3; ++kt)
        af[kt] = *(const short8*)&Abf[16 * wv + m][q4 * 8 + kt * 32];

    floatx4 acc[4] = {{0.f,0.f,0.f,0.f}, {0.f,0.f,0.f,0.f},
                      {0.f,0.f,0.f,0.f}, {0.f,0.f,0.f,0.f}};
    #pragma unroll
    for (int ct = 0; ct < 4; ++ct) {
        #pragma unroll
        for (int kt = 0; kt < 3; ++kt) {
            short8 bf = *(const short8*)&Wbf[ct * 16 + m][q4 * 8 + kt * 32];
            acc[ct] = __builtin_amdgcn_mfma_f32_16x16x32_bf16(af[kt], bf, acc[ct], 0, 0, 0);
        }
    }

    // epilogue: C/D layout col=lane&15, row=quad*4+reg  (m89/m91-verified)
    #pragma unroll
    for (int ct = 0; ct < 4; ++ct) {
        int col = cb + ct * 16 + m;
        float bsv = bias[col];
        int row0 = rb + 16 * wv + q4 * 4;
        #pragma unroll
        for (int i = 0; i < 4; ++i)
            out[(size_t)(row0 + i) * HDIM + col] = acc[ct][i] + bsv;
    }
}

extern "C" void kernel_launch(void* const* d_in, const int* in_sizes, int n_in,
                              void* d_out, int out_size, void* d_ws, size_t ws_size,
                              hipStream_t stream) {
    const float* x  = (const float*)d_in[0];
    const float* y  = (const float*)d_in[1];
    const float* wm = (const float*)d_in[2];
    const float* bs = (const float*)d_in[3];
    float* out = (float*)d_out;
    ushort_t* xattn = (ushort_t*)d_ws;   // BT*IDIM*2 = 1.31 MB scratch (bf16)

    k_attn<<<dim3(BT / 4), 256, 0, stream>>>(x, y, xattn);
    k_gemm_mfma<<<dim3(BT / 64, HDIM / 64), 256, 0, stream>>>(xattn, wm, bs, out);
}